// Round 1
// baseline (1303.986 us; speedup 1.0000x reference)
//
#include <hip/hip_runtime.h>
#include <math.h>

// Problem constants (fixed by the reference)
#define D_MODEL 1024
#define NHEAD   16
#define DKK     64
#define BATCH   2
#define SEQ     2048
#define MROWS   (BATCH*SEQ)   // 4096

// ---------------------------------------------------------------------------
// GEMM: C[M,N] = A[M,1024] @ W[1024,N] + bias, M=4096, N=1024, K=1024
// 128x128 tile, BK=16, 256 threads, 8x8 per thread, fp32.
// MODE 1: write head-split  out[((b*16+h)*2048+s)*64 + d]   (QKV path)
// MODE 2: write out[m*N+n] = acc + bias + resid[m*N+n]      (Wo + residual)
// ---------------------------------------------------------------------------
template<int MODE>
__global__ __launch_bounds__(256)
void gemm128(const float* __restrict__ A, const float* __restrict__ W,
             const float* __restrict__ bias, const float* __restrict__ resid,
             float* __restrict__ out)
{
    const int K = 1024, N = 1024;
    // As stored transposed: As[k][m]; pad 132 keeps float4 alignment (132%4==0)
    __shared__ float As[16][132];
    __shared__ float Ws[16][132];

    const int t  = threadIdx.x;
    const int tx = t & 15, ty = t >> 4;
    const int m0 = blockIdx.y * 128, n0 = blockIdx.x * 128;

    float acc[8][8] = {};

    // cooperative load mapping
    const int am = t >> 1;          // 0..127  (A row within tile)
    const int ac = (t & 1) * 8;     // 0 or 8  (A k-offset)
    const int wk = t >> 4;          // 0..15   (W k row)
    const int wn = (t & 15) * 8;    // 0..120  (W n offset)

    const float* Aptr = A + (size_t)(m0 + am) * K + ac;
    const float* Wptr = W + (size_t)wk * N + n0 + wn;

    for (int k0 = 0; k0 < K; k0 += 16) {
        float4 a0 = *(const float4*)(Aptr + k0);
        float4 a1 = *(const float4*)(Aptr + k0 + 4);
        float4 w0 = *(const float4*)(Wptr + (size_t)k0 * N);
        float4 w1 = *(const float4*)(Wptr + (size_t)k0 * N + 4);
        __syncthreads();   // previous iteration's compute done reading LDS
        As[ac+0][am] = a0.x; As[ac+1][am] = a0.y; As[ac+2][am] = a0.z; As[ac+3][am] = a0.w;
        As[ac+4][am] = a1.x; As[ac+5][am] = a1.y; As[ac+6][am] = a1.z; As[ac+7][am] = a1.w;
        *(float4*)&Ws[wk][wn]     = w0;
        *(float4*)&Ws[wk][wn + 4] = w1;
        __syncthreads();
        #pragma unroll
        for (int k = 0; k < 16; k++) {
            float4 a4  = *(const float4*)&As[k][ty*8];
            float4 a4b = *(const float4*)&As[k][ty*8 + 4];
            float4 b4  = *(const float4*)&Ws[k][tx*8];
            float4 b4b = *(const float4*)&Ws[k][tx*8 + 4];
            float a[8] = {a4.x,a4.y,a4.z,a4.w,a4b.x,a4b.y,a4b.z,a4b.w};
            float b[8] = {b4.x,b4.y,b4.z,b4.w,b4b.x,b4b.y,b4b.z,b4b.w};
            #pragma unroll
            for (int i = 0; i < 8; i++)
                #pragma unroll
                for (int j = 0; j < 8; j++)
                    acc[i][j] = fmaf(a[i], b[j], acc[i][j]);
        }
    }

    // epilogue
    float bs[8];
    *(float4*)&bs[0] = *(const float4*)&bias[n0 + tx*8];
    *(float4*)&bs[4] = *(const float4*)&bias[n0 + tx*8 + 4];

    #pragma unroll
    for (int i = 0; i < 8; i++) {
        const int mrow = m0 + ty*8 + i;
        float v[8];
        #pragma unroll
        for (int j = 0; j < 8; j++) v[j] = acc[i][j] + bs[j];

        if (MODE == 1) {
            const int b = mrow >> 11, s = mrow & 2047;
            const int n = n0 + tx*8;
            const int h = n >> 6, d = n & 63;
            float* op = out + (((size_t)(b*NHEAD + h))*SEQ + s)*DKK + d;
            *(float4*)op       = make_float4(v[0], v[1], v[2], v[3]);
            *(float4*)(op + 4) = make_float4(v[4], v[5], v[6], v[7]);
        } else {
            const size_t ofs = (size_t)mrow * N + n0 + tx*8;
            float4 r0 = *(const float4*)(resid + ofs);
            float4 r1 = *(const float4*)(resid + ofs + 4);
            *(float4*)(out + ofs)     = make_float4(v[0]+r0.x, v[1]+r0.y, v[2]+r0.z, v[3]+r0.w);
            *(float4*)(out + ofs + 4) = make_float4(v[4]+r1.x, v[5]+r1.y, v[6]+r1.z, v[7]+r1.w);
        }
    }
}

// ---------------------------------------------------------------------------
// Flash attention, fp32. One block = (b, h, 64-query tile). KBLK=32.
// Score role:  thread t -> q-row (t>>2), 8 k-cols ((t&3)*8+j). Q cached in regs.
// PV role:     thread t -> 4 rows ((t>>4)*4+rr) x 4 dims ((t&15)*4+i).
// P, per-row rescale factor and running denominator staged in LDS.
// ---------------------------------------------------------------------------
__global__ __launch_bounds__(256)
void attn_kernel(const float* __restrict__ Q, const float* __restrict__ K,
                 const float* __restrict__ V, float* __restrict__ ctx)
{
    const int qt = blockIdx.x;        // query tile (0..31)
    const int h  = blockIdx.y;
    const int b  = blockIdx.z;
    const int t  = threadIdx.x;

    __shared__ float Ks[32][68];   // pad 68: float4-aligned, conflict-light
    __shared__ float Vs[32][68];
    __shared__ float Ps[64][36];
    __shared__ float Sc[64];       // per-row rescale factor this iteration
    __shared__ float Ls[64];       // per-row running denominator

    const size_t bh = ((size_t)b * NHEAD + h) * SEQ;
    const int s0 = qt * 64;

    // ---- score-role state ----
    const int srow = t >> 2;
    const int scol = t & 3;
    float q[64];
    {
        const float4* qp = (const float4*)(Q + (bh + s0 + srow) * DKK);
        #pragma unroll
        for (int i = 0; i < 16; i++) {
            float4 qv = qp[i];
            q[4*i+0] = qv.x; q[4*i+1] = qv.y; q[4*i+2] = qv.z; q[4*i+3] = qv.w;
        }
    }
    float mrun = -INFINITY;

    // ---- PV-role state ----
    const int rq = (t >> 4) * 4;
    const int dd = (t & 15) * 4;
    float o[4][4] = {};

    if (t < 64) Ls[t] = 0.f;

    // K/V load mapping
    const int kr  = t >> 3;
    const int kc0 = (t & 7) * 8;

    for (int j0 = 0; j0 < SEQ; j0 += 32) {
        // global loads (before barrier; LDS stores after)
        const float4* kp = (const float4*)(K + (bh + j0 + kr) * DKK + kc0);
        const float4* vp = (const float4*)(V + (bh + j0 + kr) * DKK + kc0);
        float4 k0v = kp[0], k1v = kp[1];
        float4 v0v = vp[0], v1v = vp[1];

        __syncthreads();   // prev PV done with Vs/Ps/Sc; (iter0: covers Ls init)
        *(float4*)&Ks[kr][kc0]     = k0v;
        *(float4*)&Ks[kr][kc0 + 4] = k1v;
        *(float4*)&Vs[kr][kc0]     = v0v;
        *(float4*)&Vs[kr][kc0 + 4] = v1v;
        __syncthreads();

        // ---- scores + online softmax ----
        float s[8];
        #pragma unroll
        for (int j = 0; j < 8; j++) {
            const int kc = scol * 8 + j;
            float a = 0.f;
            #pragma unroll
            for (int d0 = 0; d0 < 64; d0 += 4) {
                float4 k4 = *(const float4*)&Ks[kc][d0];
                a = fmaf(q[d0+0], k4.x, a);
                a = fmaf(q[d0+1], k4.y, a);
                a = fmaf(q[d0+2], k4.z, a);
                a = fmaf(q[d0+3], k4.w, a);
            }
            s[j] = a * 0.125f;   // 1/sqrt(64)
        }
        float mb = s[0];
        #pragma unroll
        for (int j = 1; j < 8; j++) mb = fmaxf(mb, s[j]);
        mb = fmaxf(mb, __shfl_xor(mb, 1));
        mb = fmaxf(mb, __shfl_xor(mb, 2));
        const float mn    = fmaxf(mrun, mb);
        const float scale = __expf(mrun - mn);
        mrun = mn;
        float lp = 0.f;
        #pragma unroll
        for (int j = 0; j < 8; j++) {
            float p = __expf(s[j] - mn);
            lp += p;
            Ps[srow][scol*8 + j] = p;
        }
        lp += __shfl_xor(lp, 1);
        lp += __shfl_xor(lp, 2);
        if (scol == 0) {
            Sc[srow] = scale;
            Ls[srow] = Ls[srow] * scale + lp;
        }
        __syncthreads();

        // ---- PV accumulate ----
        float scr[4];
        #pragma unroll
        for (int rr = 0; rr < 4; rr++) scr[rr] = Sc[rq + rr];
        #pragma unroll
        for (int rr = 0; rr < 4; rr++)
            #pragma unroll
            for (int i = 0; i < 4; i++) o[rr][i] *= scr[rr];

        #pragma unroll
        for (int k0 = 0; k0 < 32; k0 += 4) {
            float p[4][4];
            #pragma unroll
            for (int rr = 0; rr < 4; rr++) {
                float4 p4 = *(const float4*)&Ps[rq + rr][k0];
                p[rr][0] = p4.x; p[rr][1] = p4.y; p[rr][2] = p4.z; p[rr][3] = p4.w;
            }
            #pragma unroll
            for (int kk = 0; kk < 4; kk++) {
                float4 v4 = *(const float4*)&Vs[k0 + kk][dd];
                #pragma unroll
                for (int rr = 0; rr < 4; rr++) {
                    o[rr][0] = fmaf(p[rr][kk], v4.x, o[rr][0]);
                    o[rr][1] = fmaf(p[rr][kk], v4.y, o[rr][1]);
                    o[rr][2] = fmaf(p[rr][kk], v4.z, o[rr][2]);
                    o[rr][3] = fmaf(p[rr][kk], v4.w, o[rr][3]);
                }
            }
        }
    }

    // final normalize + write context in [B,S,D] layout
    #pragma unroll
    for (int rr = 0; rr < 4; rr++) {
        const float inv = 1.f / Ls[rq + rr];
        float* cp = ctx + ((size_t)b*SEQ + s0 + rq + rr) * D_MODEL + h*DKK + dd;
        *(float4*)cp = make_float4(o[rr][0]*inv, o[rr][1]*inv, o[rr][2]*inv, o[rr][3]*inv);
    }
}

// ---------------------------------------------------------------------------
// Row LayerNorm: one block per row of 1024.
// ---------------------------------------------------------------------------
__global__ __launch_bounds__(256)
void ln_kernel(const float* __restrict__ hbuf, const float* __restrict__ gamma,
               const float* __restrict__ beta, float* __restrict__ out)
{
    const int row = blockIdx.x;
    const int t = threadIdx.x;
    const float* hp = hbuf + (size_t)row * D_MODEL;
    float4 v = ((const float4*)hp)[t];
    float sum = v.x + v.y + v.z + v.w;
    float sq  = v.x*v.x + v.y*v.y + v.z*v.z + v.w*v.w;
    #pragma unroll
    for (int o = 1; o <= 32; o <<= 1) {
        sum += __shfl_xor(sum, o);
        sq  += __shfl_xor(sq, o);
    }
    __shared__ float s1[4], s2[4];
    if ((t & 63) == 0) { s1[t >> 6] = sum; s2[t >> 6] = sq; }
    __syncthreads();
    sum = s1[0] + s1[1] + s1[2] + s1[3];
    sq  = s2[0] + s2[1] + s2[2] + s2[3];
    const float mean = sum * (1.0f / D_MODEL);
    const float var  = sq * (1.0f / D_MODEL) - mean * mean;
    const float inv  = rsqrtf(var + 1e-5f);
    float4 g  = ((const float4*)gamma)[t];
    float4 be = ((const float4*)beta)[t];
    float4 r;
    r.x = (v.x - mean) * inv * g.x + be.x;
    r.y = (v.y - mean) * inv * g.y + be.y;
    r.z = (v.z - mean) * inv * g.z + be.z;
    r.w = (v.w - mean) * inv * g.w + be.w;
    ((float4*)(out + (size_t)row * D_MODEL))[t] = r;
}

// ---------------------------------------------------------------------------
extern "C" void kernel_launch(void* const* d_in, const int* in_sizes, int n_in,
                              void* d_out, int out_size, void* d_ws, size_t ws_size,
                              hipStream_t stream)
{
    const float* x  = (const float*)d_in[0];
    const float* Wq = (const float*)d_in[1];
    const float* bq = (const float*)d_in[2];
    const float* Wk = (const float*)d_in[3];
    const float* bk = (const float*)d_in[4];
    const float* Wv = (const float*)d_in[5];
    const float* bv = (const float*)d_in[6];
    const float* Wo = (const float*)d_in[7];
    const float* bo = (const float*)d_in[8];
    const float* g  = (const float*)d_in[9];
    const float* be = (const float*)d_in[10];

    // workspace layout (floats): Q,K,V head-split + ctx + h  (5 x 16 MiB = 80 MiB)
    const size_t SZ = (size_t)MROWS * D_MODEL;  // 4194304
    float* qb  = (float*)d_ws;
    float* kb  = qb + SZ;
    float* vb  = kb + SZ;
    float* cx  = vb + SZ;
    float* hb  = cx + SZ;

    dim3 gg(D_MODEL / 128, MROWS / 128);  // (8, 32)
    gemm128<1><<<gg, 256, 0, stream>>>(x, Wq, bq, nullptr, qb);
    gemm128<1><<<gg, 256, 0, stream>>>(x, Wk, bk, nullptr, kb);
    gemm128<1><<<gg, 256, 0, stream>>>(x, Wv, bv, nullptr, vb);

    attn_kernel<<<dim3(SEQ / 64, NHEAD, BATCH), 256, 0, stream>>>(qb, kb, vb, cx);

    gemm128<2><<<gg, 256, 0, stream>>>(cx, Wo, bo, x, hb);

    ln_kernel<<<MROWS, 256, 0, stream>>>(hb, g, be, (float*)d_out);
}

// Round 2
// 229.693 us; speedup vs baseline: 5.6771x; 5.6771x over previous
//
#include <hip/hip_runtime.h>
#include <math.h>

#define D_MODEL 1024
#define NHEAD   16
#define DKK     64
#define BATCH   2
#define SEQ     2048
#define MROWS   (BATCH*SEQ)   // 4096

typedef __attribute__((ext_vector_type(8))) short bf16x8;   // 8 bf16 (4 VGPRs)
typedef __attribute__((ext_vector_type(4))) short bf16x4;   // 8 B
typedef __attribute__((ext_vector_type(4))) float f32x4;    // MFMA accumulator

#define MFMA(a,b,c) __builtin_amdgcn_mfma_f32_16x16x32_bf16((a),(b),(c),0,0,0)

__device__ __forceinline__ short f2b(float f) {
    unsigned u = __float_as_uint(f);
    unsigned r = (u + 0x7FFFu + ((u >> 16) & 1u)) >> 16;   // RNE
    return (short)r;
}

__device__ __forceinline__ void gld_lds16(const void* g, void* l) {
    __builtin_amdgcn_global_load_lds(
        (const __attribute__((address_space(1))) void*)g,
        (__attribute__((address_space(3))) void*)l, 16, 0, 0);
}

// ---------------------------------------------------------------------------
// Weight prep: W[1024][1024] f32 -> WT bf16 [N][K].  z=0..2 -> wt3, z=3 -> wot
// ---------------------------------------------------------------------------
__global__ __launch_bounds__(256)
void prep_weights(const float* __restrict__ Wq, const float* __restrict__ Wk,
                  const float* __restrict__ Wv, const float* __restrict__ Wo,
                  short* __restrict__ wt3, short* __restrict__ wot)
{
    const int z = blockIdx.z;
    const float* W = z==0 ? Wq : z==1 ? Wk : z==2 ? Wv : Wo;
    short* dst = (z < 3) ? (wt3 + (size_t)z*1024*1024) : wot;
    __shared__ float tile[32][33];
    const int tx = threadIdx.x & 31, ty = threadIdx.x >> 5;
    const int c0 = blockIdx.x*32, r0 = blockIdx.y*32;
    #pragma unroll
    for (int i = 0; i < 4; i++)
        tile[ty + i*8][tx] = W[(size_t)(r0 + ty + i*8)*1024 + c0 + tx];
    __syncthreads();
    #pragma unroll
    for (int i = 0; i < 4; i++)
        dst[(size_t)(c0 + ty + i*8)*1024 + r0 + tx] = f2b(tile[tx][ty + i*8]);
}

__global__ __launch_bounds__(256)
void convert_x(const float* __restrict__ x, short* __restrict__ xb)
{
    const int i = (blockIdx.x*256 + threadIdx.x) * 8;
    float4 a = *(const float4*)(x + i);
    float4 c = *(const float4*)(x + i + 4);
    bf16x8 v;
    v[0]=f2b(a.x); v[1]=f2b(a.y); v[2]=f2b(a.z); v[3]=f2b(a.w);
    v[4]=f2b(c.x); v[5]=f2b(c.y); v[6]=f2b(c.z); v[7]=f2b(c.w);
    *(bf16x8*)(xb + i) = v;
}

// ---------------------------------------------------------------------------
// Fused QKV GEMM: A bf16 [4096][1024] @ WT3 bf16 [3072][1024]^T.
// 128x128 tile, 4 waves (2x2), BK=32, global_load_lds + XOR unit-swizzle.
// Epilogue: proj 0/1 -> head-split bf16 [B,H,S,64]; proj 2 -> VT [B,H,64,S].
// ---------------------------------------------------------------------------
__global__ __launch_bounds__(256)
void gemm_qkv(const short* __restrict__ A, const short* __restrict__ Bt,
              const float* __restrict__ bq, const float* __restrict__ bk,
              const float* __restrict__ bv,
              short* __restrict__ qb, short* __restrict__ kb, short* __restrict__ vtb)
{
    __shared__ short As[128*32];
    __shared__ short Bs[128*32];
    const int t = threadIdx.x;
    const int w = t >> 6, lane = t & 63;
    const int r = lane & 15, g4 = lane >> 4;
    const int wr = w >> 1, wc = w & 1;
    const int m0 = blockIdx.y * 128, n0 = blockIdx.x * 128;
    const int srow = lane >> 2, su = lane & 3;

    f32x4 acc[4][4] = {};

    for (int k0 = 0; k0 < 1024; k0 += 32) {
        __syncthreads();                       // prev LDS reads done
        #pragma unroll
        for (int c = 0; c < 2; c++) {
            const int row = w*32 + c*16 + srow;
            gld_lds16(A  + (size_t)(m0+row)*1024 + k0 + 8*(su ^ ((row>>1)&3)),
                      As + w*1024 + c*512);
            gld_lds16(Bt + (size_t)(n0+row)*1024 + k0 + 8*(su ^ ((row>>1)&3)),
                      Bs + w*1024 + c*512);
        }
        __syncthreads();                       // vmcnt(0) drained by barrier
        bf16x8 af[4], bfr[4];
        #pragma unroll
        for (int m = 0; m < 4; m++) {
            const int row = wr*64 + m*16 + r;
            af[m] = *(const bf16x8*)&As[row*32 + (g4 ^ ((row>>1)&3))*8];
        }
        #pragma unroll
        for (int n = 0; n < 4; n++) {
            const int row = wc*64 + n*16 + r;
            bfr[n] = *(const bf16x8*)&Bs[row*32 + (g4 ^ ((row>>1)&3))*8];
        }
        #pragma unroll
        for (int m = 0; m < 4; m++)
            #pragma unroll
            for (int n = 0; n < 4; n++)
                acc[m][n] = MFMA(af[m], bfr[n], acc[m][n]);
    }

    #pragma unroll
    for (int n = 0; n < 4; n++) {
        const int colbase = n0 + wc*64 + n*16;
        const int proj    = colbase >> 10;        // 0=Q 1=K 2=V (uniform)
        const int within  = colbase & 1023;
        const int h       = within >> 6;
        const int d       = (within & 63) + r;
        const float* bias = (proj == 0) ? bq : (proj == 1) ? bk : bv;
        const float bval  = bias[within + r];
        #pragma unroll
        for (int m = 0; m < 4; m++) {
            const int growb = m0 + wr*64 + m*16 + g4*4;   // 4-aligned
            const int bidx  = growb >> 11;
            const int s     = growb & 2047;
            if (proj < 2) {
                short* out = (proj == 0) ? qb : kb;
                #pragma unroll
                for (int i = 0; i < 4; i++)
                    out[((size_t)(bidx*NHEAD + h)*SEQ + s + i)*DKK + d] =
                        f2b(acc[m][n][i] + bval);
            } else {
                bf16x4 pk;
                #pragma unroll
                for (int i = 0; i < 4; i++) pk[i] = f2b(acc[m][n][i] + bval);
                *(bf16x4*)(vtb + ((size_t)(bidx*NHEAD + h)*DKK + d)*SEQ + s) = pk;
            }
        }
    }
}

// ---------------------------------------------------------------------------
// Wo GEMM + bias + residual -> h fp32.  128x64 tile (waves 2x2 of 64x32).
// ---------------------------------------------------------------------------
__global__ __launch_bounds__(256)
void gemm_out(const short* __restrict__ A, const short* __restrict__ Bt,
              const float* __restrict__ bo, const float* __restrict__ resid,
              float* __restrict__ hb)
{
    __shared__ short As[128*32];
    __shared__ short Bs[64*32];
    const int t = threadIdx.x;
    const int w = t >> 6, lane = t & 63;
    const int r = lane & 15, g4 = lane >> 4;
    const int wr = w >> 1, wc = w & 1;
    const int m0 = blockIdx.y * 128, n0 = blockIdx.x * 64;
    const int srow = lane >> 2, su = lane & 3;

    f32x4 acc[4][2] = {};

    for (int k0 = 0; k0 < 1024; k0 += 32) {
        __syncthreads();
        #pragma unroll
        for (int c = 0; c < 2; c++) {
            const int row = w*32 + c*16 + srow;
            gld_lds16(A  + (size_t)(m0+row)*1024 + k0 + 8*(su ^ ((row>>1)&3)),
                      As + w*1024 + c*512);
        }
        {
            const int row = w*16 + srow;
            gld_lds16(Bt + (size_t)(n0+row)*1024 + k0 + 8*(su ^ ((row>>1)&3)),
                      Bs + w*512);
        }
        __syncthreads();
        bf16x8 af[4], bfr[2];
        #pragma unroll
        for (int m = 0; m < 4; m++) {
            const int row = wr*64 + m*16 + r;
            af[m] = *(const bf16x8*)&As[row*32 + (g4 ^ ((row>>1)&3))*8];
        }
        #pragma unroll
        for (int n = 0; n < 2; n++) {
            const int row = wc*32 + n*16 + r;
            bfr[n] = *(const bf16x8*)&Bs[row*32 + (g4 ^ ((row>>1)&3))*8];
        }
        #pragma unroll
        for (int m = 0; m < 4; m++)
            #pragma unroll
            for (int n = 0; n < 2; n++)
                acc[m][n] = MFMA(af[m], bfr[n], acc[m][n]);
    }

    #pragma unroll
    for (int n = 0; n < 2; n++) {
        const int col = n0 + wc*32 + n*16 + r;
        const float bval = bo[col];
        #pragma unroll
        for (int m = 0; m < 4; m++) {
            #pragma unroll
            for (int i = 0; i < 4; i++) {
                const int grow = m0 + wr*64 + m*16 + g4*4 + i;
                const size_t ofs = (size_t)grow*1024 + col;
                hb[ofs] = acc[m][n][i] + bval + resid[ofs];
            }
        }
    }
}

// ---------------------------------------------------------------------------
// MFMA flash attention. Block = 4 waves; wave owns 32 q-rows (2 row-groups).
// KVBLK=32. K/V read from global (L2-resident); V pre-transposed.
// P transposed through padded per-wave LDS (rows 80 B, 16-B aligned).
// ---------------------------------------------------------------------------
__global__ __launch_bounds__(256)
void attn_mfma(const short* __restrict__ Q, const short* __restrict__ K,
               const short* __restrict__ VT, short* __restrict__ ctx)
{
    const int t = threadIdx.x;
    const int w = t >> 6, lane = t & 63;
    const int r = lane & 15, g4 = lane >> 4;
    const int h = blockIdx.y, b = blockIdx.z;
    const int q0 = blockIdx.x * 128 + w * 32;

    const size_t bh = (size_t)b * NHEAD + h;
    const short* Qp = Q  + bh * SEQ * DKK;
    const short* Kp = K  + bh * SEQ * DKK;
    const short* Vp = VT + bh * DKK * SEQ;

    __shared__ short Pbuf[4][32][40];   // per-wave, 80-B rows (2-way banks)

    bf16x8 qf[2][2];
    #pragma unroll
    for (int rg = 0; rg < 2; rg++)
        #pragma unroll
        for (int ks = 0; ks < 2; ks++)
            qf[rg][ks] = *(const bf16x8*)(Qp + (q0 + rg*16 + r)*DKK + ks*32 + g4*8);

    f32x4 o[2][4] = {};
    float m_[2][4], l_[2][4];
    #pragma unroll
    for (int rg = 0; rg < 2; rg++)
        #pragma unroll
        for (int i = 0; i < 4; i++) { m_[rg][i] = -INFINITY; l_[rg][i] = 0.f; }

    bf16x8 kf[2][2];
    #pragma unroll
    for (int kt = 0; kt < 2; kt++)
        #pragma unroll
        for (int ks = 0; ks < 2; ks++)
            kf[kt][ks] = *(const bf16x8*)(Kp + (kt*16 + r)*DKK + ks*32 + g4*8);

    for (int j0 = 0; j0 < SEQ; j0 += 32) {
        bf16x8 vf[4];
        #pragma unroll
        for (int gg = 0; gg < 4; gg++)
            vf[gg] = *(const bf16x8*)(Vp + (gg*16 + r)*SEQ + j0 + g4*8);

        #pragma unroll
        for (int rg = 0; rg < 2; rg++) {
            f32x4 sa[2];
            #pragma unroll
            for (int kt = 0; kt < 2; kt++) {
                f32x4 a0 = {0.f, 0.f, 0.f, 0.f};
                a0 = MFMA(qf[rg][0], kf[kt][0], a0);
                a0 = MFMA(qf[rg][1], kf[kt][1], a0);
                sa[kt] = a0 * 0.125f;               // 1/sqrt(64)
            }
            float mx[4], sc[4], rs[4];
            #pragma unroll
            for (int i = 0; i < 4; i++) mx[i] = fmaxf(sa[0][i], sa[1][i]);
            #pragma unroll
            for (int dd = 1; dd < 16; dd <<= 1)
                #pragma unroll
                for (int i = 0; i < 4; i++) mx[i] = fmaxf(mx[i], __shfl_xor(mx[i], dd));
            #pragma unroll
            for (int i = 0; i < 4; i++) {
                const float mn = fmaxf(m_[rg][i], mx[i]);
                sc[i] = __expf(m_[rg][i] - mn);
                m_[rg][i] = mn;
                rs[i] = 0.f;
            }
            f32x4 p[2];
            #pragma unroll
            for (int kt = 0; kt < 2; kt++)
                #pragma unroll
                for (int i = 0; i < 4; i++) {
                    const float pv = __expf(sa[kt][i] - m_[rg][i]);
                    p[kt][i] = pv; rs[i] += pv;
                }
            #pragma unroll
            for (int dd = 1; dd < 16; dd <<= 1)
                #pragma unroll
                for (int i = 0; i < 4; i++) rs[i] += __shfl_xor(rs[i], dd);
            #pragma unroll
            for (int i = 0; i < 4; i++) l_[rg][i] = l_[rg][i]*sc[i] + rs[i];
            // P -> LDS (D layout: row=g4*4+i, col=kt*16+r)
            #pragma unroll
            for (int kt = 0; kt < 2; kt++)
                #pragma unroll
                for (int i = 0; i < 4; i++)
                    Pbuf[w][rg*16 + g4*4 + i][kt*16 + r] = f2b(p[kt][i]);
            // rescale O
            #pragma unroll
            for (int gg = 0; gg < 4; gg++)
                #pragma unroll
                for (int i = 0; i < 4; i++) o[rg][gg][i] *= sc[i];
        }

        // register-prefetch next K tile (hides under PV)
        if (j0 + 32 < SEQ) {
            #pragma unroll
            for (int kt = 0; kt < 2; kt++)
                #pragma unroll
                for (int ks = 0; ks < 2; ks++)
                    kf[kt][ks] = *(const bf16x8*)(Kp + (j0 + 32 + kt*16 + r)*DKK + ks*32 + g4*8);
        }

        // PV: P as A-frag (row=r, k=g4*8+j), V as B-frag from VT
        #pragma unroll
        for (int rg = 0; rg < 2; rg++) {
            bf16x8 pf = *(const bf16x8*)&Pbuf[w][rg*16 + r][g4*8];
            #pragma unroll
            for (int gg = 0; gg < 4; gg++)
                o[rg][gg] = MFMA(pf, vf[gg], o[rg][gg]);
        }
    }

    #pragma unroll
    for (int rg = 0; rg < 2; rg++) {
        float inv[4];
        #pragma unroll
        for (int i = 0; i < 4; i++) inv[i] = 1.f / l_[rg][i];
        #pragma unroll
        for (int gg = 0; gg < 4; gg++)
            #pragma unroll
            for (int i = 0; i < 4; i++) {
                const int q = q0 + rg*16 + g4*4 + i;
                ctx[((size_t)b*SEQ + q)*D_MODEL + h*DKK + gg*16 + r] =
                    f2b(o[rg][gg][i] * inv[i]);
            }
    }
}

// ---------------------------------------------------------------------------
// Row LayerNorm (fp32 in/out)
// ---------------------------------------------------------------------------
__global__ __launch_bounds__(256)
void ln_kernel(const float* __restrict__ hbuf, const float* __restrict__ gamma,
               const float* __restrict__ beta, float* __restrict__ out)
{
    const int row = blockIdx.x;
    const int t = threadIdx.x;
    const float* hp = hbuf + (size_t)row * D_MODEL;
    float4 v = ((const float4*)hp)[t];
    float sum = v.x + v.y + v.z + v.w;
    float sq  = v.x*v.x + v.y*v.y + v.z*v.z + v.w*v.w;
    #pragma unroll
    for (int o = 1; o <= 32; o <<= 1) {
        sum += __shfl_xor(sum, o);
        sq  += __shfl_xor(sq, o);
    }
    __shared__ float s1[4], s2[4];
    if ((t & 63) == 0) { s1[t >> 6] = sum; s2[t >> 6] = sq; }
    __syncthreads();
    sum = s1[0] + s1[1] + s1[2] + s1[3];
    sq  = s2[0] + s2[1] + s2[2] + s2[3];
    const float mean = sum * (1.0f / D_MODEL);
    const float var  = sq * (1.0f / D_MODEL) - mean * mean;
    const float inv  = rsqrtf(var + 1e-5f);
    float4 g  = ((const float4*)gamma)[t];
    float4 be = ((const float4*)beta)[t];
    float4 rr;
    rr.x = (v.x - mean) * inv * g.x + be.x;
    rr.y = (v.y - mean) * inv * g.y + be.y;
    rr.z = (v.z - mean) * inv * g.z + be.z;
    rr.w = (v.w - mean) * inv * g.w + be.w;
    ((float4*)(out + (size_t)row * D_MODEL))[t] = rr;
}

// ---------------------------------------------------------------------------
extern "C" void kernel_launch(void* const* d_in, const int* in_sizes, int n_in,
                              void* d_out, int out_size, void* d_ws, size_t ws_size,
                              hipStream_t stream)
{
    const float* x  = (const float*)d_in[0];
    const float* Wq = (const float*)d_in[1];
    const float* bq = (const float*)d_in[2];
    const float* Wk = (const float*)d_in[3];
    const float* bk = (const float*)d_in[4];
    const float* Wv = (const float*)d_in[5];
    const float* bv = (const float*)d_in[6];
    const float* Wo = (const float*)d_in[7];
    const float* bo = (const float*)d_in[8];
    const float* g  = (const float*)d_in[9];
    const float* be = (const float*)d_in[10];

    // workspace: xb 8MB | wt3 6MB | wot 2MB | qb 8 | kb 8 | vtb 8 | cxb 8 | hb 16
    short* xb  = (short*)d_ws;
    short* wt3 = xb  + (size_t)4096*1024;
    short* wot = wt3 + (size_t)3072*1024;
    short* qb  = wot + (size_t)1024*1024;
    short* kb  = qb  + (size_t)4096*1024;
    short* vtb = kb  + (size_t)4096*1024;
    short* cxb = vtb + (size_t)4096*1024;
    float* hb  = (float*)(cxb + (size_t)4096*1024);

    prep_weights<<<dim3(32,32,4), 256, 0, stream>>>(Wq, Wk, Wv, Wo, wt3, wot);
    convert_x  <<<2048, 256, 0, stream>>>(x, xb);
    gemm_qkv   <<<dim3(24,32), 256, 0, stream>>>(xb, wt3, bq, bk, bv, qb, kb, vtb);
    attn_mfma  <<<dim3(SEQ/128, NHEAD, BATCH), 256, 0, stream>>>(qb, kb, vtb, cxb);
    gemm_out   <<<dim3(16,32), 256, 0, stream>>>(cxb, wot, bo, x, hb);
    ln_kernel  <<<MROWS, 256, 0, stream>>>(hb, g, be, (float*)d_out);
}

// Round 3
// 208.333 us; speedup vs baseline: 6.2591x; 1.1025x over previous
//
#include <hip/hip_runtime.h>
#include <math.h>

#define D_MODEL 1024
#define NHEAD   16
#define DKK     64
#define BATCH   2
#define SEQ     2048
#define MROWS   (BATCH*SEQ)   // 4096

typedef __attribute__((ext_vector_type(8)))  short bf16x8;   // 8 bf16 (4 VGPRs)
typedef __attribute__((ext_vector_type(4)))  short bf16x4;   // 8 B
typedef __attribute__((ext_vector_type(4)))  float f32x4;    // 16x16 accumulator
typedef __attribute__((ext_vector_type(16))) float f32x16;   // 32x32 accumulator

#define MFMA(a,b,c)   __builtin_amdgcn_mfma_f32_16x16x32_bf16((a),(b),(c),0,0,0)
#define MFMA32(a,b,c) __builtin_amdgcn_mfma_f32_32x32x16_bf16((a),(b),(c),0,0,0)

__device__ __forceinline__ short f2b(float f) {
    unsigned u = __float_as_uint(f);
    unsigned r = (u + 0x7FFFu + ((u >> 16) & 1u)) >> 16;   // RNE
    return (short)r;
}

__device__ __forceinline__ void gld_lds16(const void* g, void* l) {
    __builtin_amdgcn_global_load_lds(
        (const __attribute__((address_space(1))) void*)g,
        (__attribute__((address_space(3))) void*)l, 16, 0, 0);
}

// ---------------------------------------------------------------------------
// Weight prep: W[1024][1024] f32 -> WT bf16 [N][K].  z=0..2 -> wt3, z=3 -> wot
// ---------------------------------------------------------------------------
__global__ __launch_bounds__(256)
void prep_weights(const float* __restrict__ Wq, const float* __restrict__ Wk,
                  const float* __restrict__ Wv, const float* __restrict__ Wo,
                  short* __restrict__ wt3, short* __restrict__ wot)
{
    const int z = blockIdx.z;
    const float* W = z==0 ? Wq : z==1 ? Wk : z==2 ? Wv : Wo;
    short* dst = (z < 3) ? (wt3 + (size_t)z*1024*1024) : wot;
    __shared__ float tile[32][33];
    const int tx = threadIdx.x & 31, ty = threadIdx.x >> 5;
    const int c0 = blockIdx.x*32, r0 = blockIdx.y*32;
    #pragma unroll
    for (int i = 0; i < 4; i++)
        tile[ty + i*8][tx] = W[(size_t)(r0 + ty + i*8)*1024 + c0 + tx];
    __syncthreads();
    #pragma unroll
    for (int i = 0; i < 4; i++)
        dst[(size_t)(c0 + ty + i*8)*1024 + r0 + tx] = f2b(tile[tx][ty + i*8]);
}

__global__ __launch_bounds__(256)
void convert_x(const float* __restrict__ x, short* __restrict__ xb)
{
    const int i = (blockIdx.x*256 + threadIdx.x) * 8;
    float4 a = *(const float4*)(x + i);
    float4 c = *(const float4*)(x + i + 4);
    bf16x8 v;
    v[0]=f2b(a.x); v[1]=f2b(a.y); v[2]=f2b(a.z); v[3]=f2b(a.w);
    v[4]=f2b(c.x); v[5]=f2b(c.y); v[6]=f2b(c.z); v[7]=f2b(c.w);
    *(bf16x8*)(xb + i) = v;
}

// ---------------------------------------------------------------------------
// Fused QKV GEMM: A bf16 [4096][1024] @ WT3 bf16 [3072][1024]^T.
// 128x128 tile, 4 waves (2x2), BK=32, global_load_lds + XOR unit-swizzle.
// Epilogue: proj 0/1 -> head-split bf16 [B,H,S,64]; proj 2 -> VT [B,H,64,S].
// ---------------------------------------------------------------------------
__global__ __launch_bounds__(256)
void gemm_qkv(const short* __restrict__ A, const short* __restrict__ Bt,
              const float* __restrict__ bq, const float* __restrict__ bk,
              const float* __restrict__ bv,
              short* __restrict__ qb, short* __restrict__ kb, short* __restrict__ vtb)
{
    __shared__ short As[128*32];
    __shared__ short Bs[128*32];
    const int t = threadIdx.x;
    const int w = t >> 6, lane = t & 63;
    const int r = lane & 15, g4 = lane >> 4;
    const int wr = w >> 1, wc = w & 1;
    const int m0 = blockIdx.y * 128, n0 = blockIdx.x * 128;
    const int srow = lane >> 2, su = lane & 3;

    f32x4 acc[4][4] = {};

    for (int k0 = 0; k0 < 1024; k0 += 32) {
        __syncthreads();
        #pragma unroll
        for (int c = 0; c < 2; c++) {
            const int row = w*32 + c*16 + srow;
            gld_lds16(A  + (size_t)(m0+row)*1024 + k0 + 8*(su ^ ((row>>1)&3)),
                      As + w*1024 + c*512);
            gld_lds16(Bt + (size_t)(n0+row)*1024 + k0 + 8*(su ^ ((row>>1)&3)),
                      Bs + w*1024 + c*512);
        }
        __syncthreads();
        bf16x8 af[4], bfr[4];
        #pragma unroll
        for (int m = 0; m < 4; m++) {
            const int row = wr*64 + m*16 + r;
            af[m] = *(const bf16x8*)&As[row*32 + (g4 ^ ((row>>1)&3))*8];
        }
        #pragma unroll
        for (int n = 0; n < 4; n++) {
            const int row = wc*64 + n*16 + r;
            bfr[n] = *(const bf16x8*)&Bs[row*32 + (g4 ^ ((row>>1)&3))*8];
        }
        #pragma unroll
        for (int m = 0; m < 4; m++)
            #pragma unroll
            for (int n = 0; n < 4; n++)
                acc[m][n] = MFMA(af[m], bfr[n], acc[m][n]);
    }

    #pragma unroll
    for (int n = 0; n < 4; n++) {
        const int colbase = n0 + wc*64 + n*16;
        const int proj    = colbase >> 10;
        const int within  = colbase & 1023;
        const int h       = within >> 6;
        const int d       = (within & 63) + r;
        const float* bias = (proj == 0) ? bq : (proj == 1) ? bk : bv;
        const float bval  = bias[within + r];
        #pragma unroll
        for (int m = 0; m < 4; m++) {
            const int growb = m0 + wr*64 + m*16 + g4*4;
            const int bidx  = growb >> 11;
            const int s     = growb & 2047;
            if (proj < 2) {
                short* out = (proj == 0) ? qb : kb;
                #pragma unroll
                for (int i = 0; i < 4; i++)
                    out[((size_t)(bidx*NHEAD + h)*SEQ + s + i)*DKK + d] =
                        f2b(acc[m][n][i] + bval);
            } else {
                bf16x4 pk;
                #pragma unroll
                for (int i = 0; i < 4; i++) pk[i] = f2b(acc[m][n][i] + bval);
                *(bf16x4*)(vtb + ((size_t)(bidx*NHEAD + h)*DKK + d)*SEQ + s) = pk;
            }
        }
    }
}

// ---------------------------------------------------------------------------
// Wo GEMM + bias + residual -> h fp32.  128x64 tile (waves 2x2 of 64x32).
// ---------------------------------------------------------------------------
__global__ __launch_bounds__(256)
void gemm_out(const short* __restrict__ A, const short* __restrict__ Bt,
              const float* __restrict__ bo, const float* __restrict__ resid,
              float* __restrict__ hb)
{
    __shared__ short As[128*32];
    __shared__ short Bs[64*32];
    const int t = threadIdx.x;
    const int w = t >> 6, lane = t & 63;
    const int r = lane & 15, g4 = lane >> 4;
    const int wr = w >> 1, wc = w & 1;
    const int m0 = blockIdx.y * 128, n0 = blockIdx.x * 64;
    const int srow = lane >> 2, su = lane & 3;

    f32x4 acc[4][2] = {};

    for (int k0 = 0; k0 < 1024; k0 += 32) {
        __syncthreads();
        #pragma unroll
        for (int c = 0; c < 2; c++) {
            const int row = w*32 + c*16 + srow;
            gld_lds16(A  + (size_t)(m0+row)*1024 + k0 + 8*(su ^ ((row>>1)&3)),
                      As + w*1024 + c*512);
        }
        {
            const int row = w*16 + srow;
            gld_lds16(Bt + (size_t)(n0+row)*1024 + k0 + 8*(su ^ ((row>>1)&3)),
                      Bs + w*512);
        }
        __syncthreads();
        bf16x8 af[4], bfr[2];
        #pragma unroll
        for (int m = 0; m < 4; m++) {
            const int row = wr*64 + m*16 + r;
            af[m] = *(const bf16x8*)&As[row*32 + (g4 ^ ((row>>1)&3))*8];
        }
        #pragma unroll
        for (int n = 0; n < 2; n++) {
            const int row = wc*32 + n*16 + r;
            bfr[n] = *(const bf16x8*)&Bs[row*32 + (g4 ^ ((row>>1)&3))*8];
        }
        #pragma unroll
        for (int m = 0; m < 4; m++)
            #pragma unroll
            for (int n = 0; n < 2; n++)
                acc[m][n] = MFMA(af[m], bfr[n], acc[m][n]);
    }

    #pragma unroll
    for (int n = 0; n < 2; n++) {
        const int col = n0 + wc*32 + n*16 + r;
        const float bval = bo[col];
        #pragma unroll
        for (int m = 0; m < 4; m++) {
            #pragma unroll
            for (int i = 0; i < 4; i++) {
                const int grow = m0 + wr*64 + m*16 + g4*4 + i;
                const size_t ofs = (size_t)grow*1024 + col;
                hb[ofs] = acc[m][n][i] + bval + resid[ofs];
            }
        }
    }
}

// ---------------------------------------------------------------------------
// Swapped-QK 32x32 MFMA flash attention (m214 structure, D=64).
// Wave owns 32 q-rows. KVBLK=64. No LDS, no barriers. K/V direct from
// global (L2-resident); V pre-transposed. P stays in registers (T12).
// Defer-max (T13): O-rescale broadcast only when running max grows.
// S^T layout: lane owns q=lane&31; k = (reg&3)+8*(reg>>2)+4*(lane>>5).
// O layout:   lane owns d=gg*32+lane&31; q rows = crow(reg,hi).
// ---------------------------------------------------------------------------
#define CSC 0.18033688f    // 0.125 * log2(e)

#define ATT_TILE(KFC, KFN, J0, PJ)                                             \
{                                                                              \
    bf16x8 vf[8];                                                              \
    _Pragma("unroll")                                                          \
    for (int i = 0; i < 8; i++)                                                \
        vf[i] = *(const bf16x8*)(Vp + ((size_t)((i&1)*32 + l31))*SEQ + (J0) + (i>>1)*16 + hi*8); \
    f32x16 s0 = {}, s1 = {};                                                   \
    _Pragma("unroll")                                                          \
    for (int d0 = 0; d0 < 4; d0++) s0 = MFMA32(KFC[d0],   qf[d0], s0);         \
    _Pragma("unroll")                                                          \
    for (int d0 = 0; d0 < 4; d0++) s1 = MFMA32(KFC[4+d0], qf[d0], s1);         \
    _Pragma("unroll")                                                          \
    for (int i = 0; i < 8; i++)                                                \
        KFN[i] = *(const bf16x8*)(Kp + ((size_t)((PJ) + (i>>2)*32 + l31))*DKK + (i&3)*16 + hi*8); \
    float pm = s0[0];                                                          \
    _Pragma("unroll")                                                          \
    for (int r = 1; r < 16; r++) pm = fmaxf(pm, s0[r]);                        \
    _Pragma("unroll")                                                          \
    for (int r = 0; r < 16; r++) pm = fmaxf(pm, s1[r]);                        \
    pm = fmaxf(pm, __shfl_xor(pm, 32));                                        \
    if (!__all(pm - mrow <= 44.0f)) {   /* rare: max grew (T13) */             \
        const float mnew = fmaxf(mrow, pm);                                    \
        const float scf  = exp2f((mrow - mnew) * CSC);                         \
        mrow = mnew; lrow *= scf;                                              \
        const int sb = __float_as_int(scf);                                    \
        _Pragma("unroll")                                                      \
        for (int r = 0; r < 16; r++) {                                         \
            const float sc = __int_as_float(                                   \
                __builtin_amdgcn_ds_bpermute(((r&3)+8*(r>>2)+4*hi)*4, sb));    \
            o0[r] *= sc; o1[r] *= sc;                                          \
        }                                                                      \
    }                                                                          \
    const float nb = -mrow * CSC;                                              \
    float rs = 0.f;                                                            \
    _Pragma("unroll")                                                          \
    for (int r = 0; r < 16; r++) { s0[r] = exp2f(fmaf(s0[r], CSC, nb)); rs += s0[r]; } \
    _Pragma("unroll")                                                          \
    for (int r = 0; r < 16; r++) { s1[r] = exp2f(fmaf(s1[r], CSC, nb)); rs += s1[r]; } \
    rs += __shfl_xor(rs, 32);                                                  \
    lrow += rs;                                                                \
    _Pragma("unroll")                                                          \
    for (int ks = 0; ks < 4; ks++) {   /* T12: cvt_pk + permlane32_swap */     \
        const int g = (ks & 1) * 8;                                            \
        float e0,e1,e2,e3,e4,e5,e6,e7;                                         \
        if (ks < 2) { e0=s0[g+0];e1=s0[g+1];e2=s0[g+2];e3=s0[g+3];             \
                      e4=s0[g+4];e5=s0[g+5];e6=s0[g+6];e7=s0[g+7]; }           \
        else        { e0=s1[g+0];e1=s1[g+1];e2=s1[g+2];e3=s1[g+3];             \
                      e4=s1[g+4];e5=s1[g+5];e6=s1[g+6];e7=s1[g+7]; }           \
        unsigned u0,u1,u2,u3;                                                  \
        asm("v_cvt_pk_bf16_f32 %0, %1, %2" : "=v"(u0) : "v"(e0), "v"(e1));     \
        asm("v_cvt_pk_bf16_f32 %0, %1, %2" : "=v"(u1) : "v"(e2), "v"(e3));     \
        asm("v_cvt_pk_bf16_f32 %0, %1, %2" : "=v"(u2) : "v"(e4), "v"(e5));     \
        asm("v_cvt_pk_bf16_f32 %0, %1, %2" : "=v"(u3) : "v"(e6), "v"(e7));     \
        auto rA = __builtin_amdgcn_permlane32_swap(u0, u2, false, false);      \
        auto rB = __builtin_amdgcn_permlane32_swap(u1, u3, false, false);      \
        union { unsigned u[4]; bf16x8 v; } pa;                                 \
        pa.u[0] = rA[0]; pa.u[1] = rB[0]; pa.u[2] = rA[1]; pa.u[3] = rB[1];    \
        o0 = MFMA32(pa.v, vf[ks*2+0], o0);                                     \
        o1 = MFMA32(pa.v, vf[ks*2+1], o1);                                     \
    }                                                                          \
}

__global__ __launch_bounds__(256, 2)
void attn_mfma(const short* __restrict__ Q, const short* __restrict__ K,
               const short* __restrict__ VT, short* __restrict__ ctx)
{
    const int t = threadIdx.x;
    const int w = t >> 6, lane = t & 63;
    const int l31 = lane & 31, hi = lane >> 5;
    const int h = blockIdx.y, b = blockIdx.z;
    const int q0 = blockIdx.x * 128 + w * 32;

    const size_t bh = (size_t)b * NHEAD + h;
    const short* Qp = Q  + bh * SEQ * DKK;
    const short* Kp = K  + bh * SEQ * DKK;
    const short* Vp = VT + bh * DKK * SEQ;

    // Q B-frags: lane holds Q[q0+l31][d0*16 + hi*8 + j]
    bf16x8 qf[4];
    #pragma unroll
    for (int d0 = 0; d0 < 4; d0++)
        qf[d0] = *(const bf16x8*)(Qp + (size_t)(q0 + l31)*DKK + d0*16 + hi*8);

    f32x16 o0 = {}, o1 = {};
    float mrow = -INFINITY, lrow = 0.f;

    // K A-frags, double-buffered in registers
    bf16x8 kfA[8], kfB[8];
    #pragma unroll
    for (int i = 0; i < 8; i++)
        kfA[i] = *(const bf16x8*)(Kp + ((size_t)((i>>2)*32 + l31))*DKK + (i&3)*16 + hi*8);

    #pragma unroll 1
    for (int j0 = 0; j0 < SEQ; j0 += 128) {
        ATT_TILE(kfA, kfB, j0,      j0 + 64)
        ATT_TILE(kfB, kfA, j0 + 64, (j0 + 128) & (SEQ - 1))
    }

    // epilogue: broadcast 1/l to O rows, write ctx [B,S,1024] bf16
    const float li = 1.f / lrow;
    const int lb = __float_as_int(li);
    #pragma unroll
    for (int r = 0; r < 16; r++) {
        const int crow = (r&3) + 8*(r>>2) + 4*hi;
        const float lv = __int_as_float(__builtin_amdgcn_ds_bpermute(crow*4, lb));
        const size_t base = ((size_t)b*SEQ + q0 + crow)*D_MODEL + h*DKK + l31;
        ctx[base]      = f2b(o0[r] * lv);
        ctx[base + 32] = f2b(o1[r] * lv);
    }
}

// ---------------------------------------------------------------------------
// Row LayerNorm (fp32 in/out)
// ---------------------------------------------------------------------------
__global__ __launch_bounds__(256)
void ln_kernel(const float* __restrict__ hbuf, const float* __restrict__ gamma,
               const float* __restrict__ beta, float* __restrict__ out)
{
    const int row = blockIdx.x;
    const int t = threadIdx.x;
    const float* hp = hbuf + (size_t)row * D_MODEL;
    float4 v = ((const float4*)hp)[t];
    float sum = v.x + v.y + v.z + v.w;
    float sq  = v.x*v.x + v.y*v.y + v.z*v.z + v.w*v.w;
    #pragma unroll
    for (int o = 1; o <= 32; o <<= 1) {
        sum += __shfl_xor(sum, o);
        sq  += __shfl_xor(sq, o);
    }
    __shared__ float s1[4], s2[4];
    if ((t & 63) == 0) { s1[t >> 6] = sum; s2[t >> 6] = sq; }
    __syncthreads();
    sum = s1[0] + s1[1] + s1[2] + s1[3];
    sq  = s2[0] + s2[1] + s2[2] + s2[3];
    const float mean = sum * (1.0f / D_MODEL);
    const float var  = sq * (1.0f / D_MODEL) - mean * mean;
    const float inv  = rsqrtf(var + 1e-5f);
    float4 g  = ((const float4*)gamma)[t];
    float4 be = ((const float4*)beta)[t];
    float4 rr;
    rr.x = (v.x - mean) * inv * g.x + be.x;
    rr.y = (v.y - mean) * inv * g.y + be.y;
    rr.z = (v.z - mean) * inv * g.z + be.z;
    rr.w = (v.w - mean) * inv * g.w + be.w;
    ((float4*)(out + (size_t)row * D_MODEL))[t] = rr;
}

// ---------------------------------------------------------------------------
extern "C" void kernel_launch(void* const* d_in, const int* in_sizes, int n_in,
                              void* d_out, int out_size, void* d_ws, size_t ws_size,
                              hipStream_t stream)
{
    const float* x  = (const float*)d_in[0];
    const float* Wq = (const float*)d_in[1];
    const float* bq = (const float*)d_in[2];
    const float* Wk = (const float*)d_in[3];
    const float* bk = (const float*)d_in[4];
    const float* Wv = (const float*)d_in[5];
    const float* bv = (const float*)d_in[6];
    const float* Wo = (const float*)d_in[7];
    const float* bo = (const float*)d_in[8];
    const float* g  = (const float*)d_in[9];
    const float* be = (const float*)d_in[10];

    short* xb  = (short*)d_ws;
    short* wt3 = xb  + (size_t)4096*1024;
    short* wot = wt3 + (size_t)3072*1024;
    short* qb  = wot + (size_t)1024*1024;
    short* kb  = qb  + (size_t)4096*1024;
    short* vtb = kb  + (size_t)4096*1024;
    short* cxb = vtb + (size_t)4096*1024;
    float* hb  = (float*)(cxb + (size_t)4096*1024);

    prep_weights<<<dim3(32,32,4), 256, 0, stream>>>(Wq, Wk, Wv, Wo, wt3, wot);
    convert_x  <<<2048, 256, 0, stream>>>(x, xb);
    gemm_qkv   <<<dim3(24,32), 256, 0, stream>>>(xb, wt3, bq, bk, bv, qb, kb, vtb);
    attn_mfma  <<<dim3(SEQ/128, NHEAD, BATCH), 256, 0, stream>>>(qb, kb, vtb, cxb);
    gemm_out   <<<dim3(16,32), 256, 0, stream>>>(cxb, wot, bo, x, hb);
    ln_kernel  <<<MROWS, 256, 0, stream>>>(hb, g, be, (float*)d_out);
}